// Round 10
// baseline (416.334 us; speedup 1.0000x reference)
//
#include <hip/hip_runtime.h>

// BatchSampler rnd10: fused kernel (4 blk/row x 1024) + 512B memset,
// FIXED cross-XCD handoff (r9 failed: plain-load counts went stale across
// XCDs -> all rows tripped validation -> heavy path -> 305us).
// Phase 1 (all blocks): capture quarter-row (raw logit >= 2.25) into LDS,
//   write entries to a private ws segment; publish count via
//   __hip_atomic_store(RELEASE, AGENT); elect finisher via
//   __hip_atomic_fetch_add(ACQ_REL, AGENT).
// Phase 2 (finisher): read counts via __hip_atomic_load(ACQUIRE, AGENT).
//   valid -> gather 4 segments -> hybrid bitonic (x desc, idx asc = exact
//   reference rank order) -> verified tail (top-p, min-p, gumbel argmax via
//   threefry-partitionable key=(0,42)).
//   counts invalid (stale/overflow) -> SELF-RECAPTURE: finisher re-streams
//   its row once (L3-warm) into LDS, then same sort+tail (~+10us not +230).
//   k inactive / recapture invalid -> verified heavy fixed-point pipeline.

#define TPB 1024
#define VOC 128256
#define V4 (VOC / 4)          // 32064
#define Q4 (V4 / 4)           // 8016 float4s per quarter-row block
#define NBINS 2048
#define SEG 640               // per-block capture segment (+12.6 sigma)
#define CAPROW (4 * SEG)      // 2560 staging entries per row
#define CAP2 2048             // sort size
#define TIE_CAP 1024
#define IMAXI 0x7fffffff
#define FIXS 1.7592186044416e13   // 2^44
#define THRK 0xC0100000u      // fkey(2.25f): raw-logit capture threshold

// ws layout (bytes)
#define WS_DONE 0                              // u32 [128] = 512 B (memset 0)
#define WS_CNT  512                            // u32 [128][4] = 2 KB
#define WS_CAP  4096                           // u64 [128][CAPROW] = 2.62 MB

__device__ __forceinline__ unsigned fkey(float x) {
  unsigned b = __float_as_uint(x);
  return b ^ ((b & 0x80000000u) ? 0xFFFFFFFFu : 0x80000000u);
}
__device__ __forceinline__ float keyf(unsigned k) {
  unsigned b = (k & 0x80000000u) ? (k ^ 0x80000000u) : ~k;
  return __uint_as_float(b);
}
__device__ __forceinline__ unsigned rotl32(unsigned v, int r) {
  return (v << r) | (v >> (32 - r));
}

// JAX threefry2x32, key=(0,42), partitionable path: counters (0,i), out o1^o2.
__device__ __forceinline__ float gumbel_at(unsigned i) {
  const unsigned ks1 = 42u;
  const unsigned ks2 = 0x1BD11BDAu ^ 42u;
  unsigned x0 = 0u;
  unsigned x1 = i + ks1;
  x0 += x1; x1 = rotl32(x1, 13); x1 ^= x0;
  x0 += x1; x1 = rotl32(x1, 15); x1 ^= x0;
  x0 += x1; x1 = rotl32(x1, 26); x1 ^= x0;
  x0 += x1; x1 = rotl32(x1, 6);  x1 ^= x0;
  x0 += ks1; x1 += ks2 + 1u;
  x0 += x1; x1 = rotl32(x1, 17); x1 ^= x0;
  x0 += x1; x1 = rotl32(x1, 29); x1 ^= x0;
  x0 += x1; x1 = rotl32(x1, 16); x1 ^= x0;
  x0 += x1; x1 = rotl32(x1, 24); x1 ^= x0;
  x0 += ks2; x1 += 0u + 2u;
  x0 += x1; x1 = rotl32(x1, 13); x1 ^= x0;
  x0 += x1; x1 = rotl32(x1, 15); x1 ^= x0;
  x0 += x1; x1 = rotl32(x1, 26); x1 ^= x0;
  x0 += x1; x1 = rotl32(x1, 6);  x1 ^= x0;
  x0 += 0u; x1 += ks1 + 3u;
  x0 += x1; x1 = rotl32(x1, 17); x1 ^= x0;
  x0 += x1; x1 = rotl32(x1, 29); x1 ^= x0;
  x0 += x1; x1 = rotl32(x1, 16); x1 ^= x0;
  x0 += x1; x1 = rotl32(x1, 24); x1 ^= x0;
  x0 += ks1; x1 += ks2 + 4u;
  x0 += x1; x1 = rotl32(x1, 13); x1 ^= x0;
  x0 += x1; x1 = rotl32(x1, 15); x1 ^= x0;
  x0 += x1; x1 = rotl32(x1, 26); x1 ^= x0;
  x0 += x1; x1 = rotl32(x1, 6);  x1 ^= x0;
  x0 += ks2; x1 += 0u + 5u;
  unsigned bits = x0 ^ x1;
  unsigned fb = (bits >> 9) | 0x3f800000u;
  float f = __uint_as_float(fb) - 1.0f;
  float u = (f > 0.0f) ? f : 1.17549435e-38f;
  return -logf(-logf(u));
}

// In-register bitonic merge step: strides maxs..1 (maxs<=32) inside a 64-wave.
__device__ __forceinline__ unsigned long long bmerge(
    unsigned long long v, int i, int size, int maxs) {
  const bool up = ((i & size) == 0);
  for (int s = maxs; s > 0; s >>= 1) {
    unsigned long long p = __shfl_xor(v, s, 64);
    bool keep_min = (up == ((i & s) == 0));
    bool take = keep_min ? (p < v) : (p > v);
    if (take) v = p;
  }
  return v;
}

// Inclusive suffix scan, generic block size (n/tpb <= 4)
__device__ __forceinline__ void scan32g(unsigned* H, int n, int tid, int tpb) {
  for (int d = 1; d < n; d <<= 1) {
    unsigned v[4]; int c = 0;
    for (int i = tid; i < n; i += tpb) {
      v[c] = H[i] + ((i + d < n) ? H[i + d] : 0u);
      ++c;
    }
    __syncthreads();
    c = 0;
    for (int i = tid; i < n; i += tpb) { H[i] = v[c]; ++c; }
    __syncthreads();
  }
}
__device__ __forceinline__ void scan64(unsigned long long* H, int n, int tid) {
  for (int d = 1; d < n; d <<= 1) {
    unsigned long long v0 = 0ull, v1 = 0ull;
    int i0 = tid, i1 = tid + TPB;
    bool a0 = (i0 < n), a1 = (i1 < n);
    if (a0) { v0 = H[i0]; if (i0 + d < n) v0 += H[i0 + d]; }
    if (a1) { v1 = H[i1]; if (i1 + d < n) v1 += H[i1 + d]; }
    __syncthreads();
    if (a0) H[i0] = v0;
    if (a1) H[i1] = v1;
    __syncthreads();
  }
}

// Full-row stream for heavy path (TPB threads)
#define FOR_ALL(...)                                                          \
  for (int c_ = 0; c_ < 32; ++c_) {                                           \
    const int i4_ = c_ * TPB + tid;                                           \
    if (i4_ < V4) {                                                           \
      const float4 L_ = ((const float4*)rowp)[i4_];                           \
      const float xs_[4] = { L_.x / tclamp, L_.y / tclamp,                    \
                             L_.z / tclamp, L_.w / tclamp };                  \
      const int base_ = i4_ * 4;                                              \
      for (int j_ = 0; j_ < 4; ++j_) {                                        \
        const int idx = base_ + j_; const float x = xs_[j_];                  \
        __VA_ARGS__                                                           \
      }                                                                       \
    }                                                                         \
  }

extern "C" __global__ void __launch_bounds__(TPB)
sampler_fused(const float* __restrict__ logits, const float* __restrict__ temps,
              const float* __restrict__ topps, const int* __restrict__ topks,
              const float* __restrict__ minps, unsigned char* __restrict__ ws,
              int* __restrict__ out)
{
  __shared__ unsigned long long Ls[SEG];  // 5 KB capture staging
  __shared__ unsigned long long A[CAP2];  // 16 KB: sort buf / heavy u64 hist
  __shared__ unsigned Hc[NBINS];          // 8 KB: heavy counts / tie list
  __shared__ double D[TPB];               // 8 KB prefix sums
  __shared__ float redw[16];
  __shared__ int   redi[16];
  __shared__ double redd[16];
  __shared__ unsigned sh_nloc;
  __shared__ int sh_last;
  __shared__ int segoff[5];
  __shared__ int sh_bad;
  __shared__ float sh_m;
  __shared__ int sh_b0, sh_b1, sh_b2;
  __shared__ unsigned sh_above;
  __shared__ unsigned long long sh_ab64;
  __shared__ int sh_p, sh_tn, sh_I2;
  __shared__ double sh_Z3;

  const int blk = blockIdx.x;
  const int row = blk >> 2, sb = blk & 3;
  const int tid = threadIdx.x;
  const float* rowp = logits + (size_t)row * VOC;
  const float tclamp = fmaxf(temps[row], 1e-8f);

  // ==================== Phase 1: capture quarter-row ====================
  if (tid == 0) sh_nloc = 0u;
  __syncthreads();
  for (int c = 0; c < 8; ++c) {
    const int t = c * TPB + tid;
    if (t < Q4) {
      const int i4 = sb * Q4 + t;
      const float4 L = ((const float4*)rowp)[i4];
      const float v[4] = { L.x, L.y, L.z, L.w };
      const int base = i4 * 4;
      for (int j = 0; j < 4; ++j) {
        if (fkey(v[j]) >= THRK) {
          float x = v[j] / tclamp;
          unsigned kx = fkey(x);
          unsigned p = atomicAdd(&sh_nloc, 1u);
          if (p < SEG)
            Ls[p] = ((unsigned long long)(~kx) << 32) | (unsigned)(base + j);
        }
      }
    }
  }
  __syncthreads();
  const unsigned nloc = sh_nloc;    // raw count; >SEG flags overflow
  {
    unsigned long long* cap = (unsigned long long*)(ws + WS_CAP) +
                              (size_t)row * CAPROW + (size_t)sb * SEG;
    const unsigned nw = min(nloc, (unsigned)SEG);
    for (unsigned i = tid; i < nw; i += TPB) cap[i] = Ls[i];
  }
  __threadfence();                  // drain segment data stores
  if (tid == 0) {
    // release-publish our count (agent scope forces cross-XCD visibility)
    __hip_atomic_store(&((unsigned*)(ws + WS_CNT))[row * 4 + sb], nloc,
                       __ATOMIC_RELEASE, __HIP_MEMORY_SCOPE_AGENT);
    unsigned old = __hip_atomic_fetch_add(&((unsigned*)(ws + WS_DONE))[row], 1u,
                                          __ATOMIC_ACQ_REL,
                                          __HIP_MEMORY_SCOPE_AGENT);
    sh_last = (old == 3u);
  }
  __syncthreads();
  if (!sh_last) return;
  __threadfence();   // acquire side: other blocks' segments now visible

  // ==================== Phase 2: finisher ====================
  const float topp = topps[row];
  const float minp = minps[row];
  const int k = topks[row];
  const bool ka = (k > 0) && (k < VOC);

  if (tid == 0) {
    int acc = 0, bad = 0;
    for (int b = 0; b < 4; ++b) {
      segoff[b] = acc;
      unsigned c = __hip_atomic_load(&((const unsigned*)(ws + WS_CNT))[row * 4 + b],
                                     __ATOMIC_ACQUIRE, __HIP_MEMORY_SCOPE_AGENT);
      if (c > SEG) bad = 1;
      acc += (int)c;
    }
    segoff[4] = acc;
    sh_bad = bad;
  }
  __syncthreads();
  int n = segoff[4];

  bool have = false;
  if (ka && k <= TPB && !sh_bad && n >= k && n <= CAP2) {
    // ---- gather the 4 published segments ----
    const unsigned long long* capr =
        (const unsigned long long*)(ws + WS_CAP) + (size_t)row * CAPROW;
    for (int b = 0; b < 4; ++b) {
      const int off = segoff[b], cnt = segoff[b + 1] - off;
      for (int i = tid; i < cnt; i += TPB) A[off + i] = capr[b * SEG + i];
    }
    have = true;
  } else if (ka && k <= TPB) {
    // ---- mid path: self-recapture full row (L3-warm), no cross-block data
    if (tid == 0) sh_nloc = 0u;
    __syncthreads();
    for (int c = 0; c < 32; ++c) {
      const int i4 = c * TPB + tid;
      if (i4 < V4) {
        const float4 L = ((const float4*)rowp)[i4];
        const float v[4] = { L.x, L.y, L.z, L.w };
        const int base = i4 * 4;
        for (int j = 0; j < 4; ++j) {
          if (fkey(v[j]) >= THRK) {
            float x = v[j] / tclamp;
            unsigned kx = fkey(x);
            unsigned p = atomicAdd(&sh_nloc, 1u);
            if (p < CAP2)
              A[p] = ((unsigned long long)(~kx) << 32) | (unsigned)(base + j);
          }
        }
      }
    }
    __syncthreads();
    const int n2 = (int)sh_nloc;
    if (n2 >= k && n2 <= CAP2) { n = n2; have = true; }
  }

  if (have) {
    // ==================== FAST TAIL (verified r8) ====================
    for (int i = n + tid; i < CAP2; i += TPB) A[i] = ~0ull;
    __syncthreads();
    // hybrid bitonic sort, 2048 fixed: (~xkey,idx) asc == x desc, idx asc
    const int lane = tid & 63, wave = tid >> 6;
    for (int g = wave; g < 32; g += 16) {       // sizes 2..64 in-register
      const int i = g * 64 + lane;
      unsigned long long v = A[i];
      v = bmerge(v, i, 2, 1);
      v = bmerge(v, i, 4, 2);
      v = bmerge(v, i, 8, 4);
      v = bmerge(v, i, 16, 8);
      v = bmerge(v, i, 32, 16);
      v = bmerge(v, i, 64, 32);
      A[i] = v;
    }
    __syncthreads();
    for (int size = 128; size <= CAP2; size <<= 1) {
      for (int stride = size >> 1; stride >= 64; stride >>= 1) {  // cross-wave
        for (int r = 0; r < 2; ++r) {
          const int i = tid + (r << 10);
          const int j = i ^ stride;
          if (j > i) {
            unsigned long long a = A[i], b = A[j];
            bool up = ((i & size) == 0);
            if ((a > b) == up) { A[i] = b; A[j] = a; }
          }
        }
        __syncthreads();
      }
      for (int g = wave; g < 32; g += 16) {     // strides 32..1 in-register
        const int i = g * 64 + lane;
        A[i] = bmerge(A[i], i, size, 32);
      }
      __syncthreads();
    }
    // verified tail on positions 0..k-1
    const float m = keyf(~(unsigned)(A[0] >> 32));   // max x
    unsigned idx_i = 0u; float e_i = 0.0f;
    const bool valid = (tid < k);
    if (valid) {
      unsigned long long a = A[tid];
      idx_i = (unsigned)a;
      e_i = expf(keyf(~(unsigned)(a >> 32)) - m);
    }
    // wave-shuffle inclusive prefix scan of e_i
    double v = valid ? (double)e_i : 0.0;
    for (int o = 1; o < 64; o <<= 1) {
      double t = __shfl_up(v, o);
      if ((tid & 63) >= o) v += t;
    }
    if ((tid & 63) == 63) redd[tid >> 6] = v;
    __syncthreads();
    if (tid == 0) {
      double acc = 0.0;
      for (int w = 0; w < 16; ++w) { double t = redd[w]; redd[w] = acc; acc += t; }
    }
    __syncthreads();
    v += redd[tid >> 6];
    D[tid] = v;
    __syncthreads();
    const double Z1 = D[k - 1];
    const double T = (double)topp * Z1;
    if (tid == 0) sh_p = 0;
    __syncthreads();
    if (valid) {
      bool kept = (tid == 0) || (D[tid - 1] <= T);
      if (kept) atomicMax(&sh_p, tid);
    }
    __syncthreads();
    const int p2 = sh_p + 1;
    const float Z2f = (float)D[p2 - 1];
    const float e0 = expf(0.0f);                     // top element: x-m == 0
    const float thrm = minp * (e0 / Z2f);
    __syncthreads();
    if (tid == 0) sh_p = 0;
    __syncthreads();
    if (valid && tid < p2) {
      float q = e_i / Z2f;
      if (!(q < thrm)) atomicMax(&sh_p, tid);
    }
    __syncthreads();
    const int p3 = sh_p + 1;
    const float Z3f = (float)D[p3 - 1];
    float bw = -INFINITY; int bi = IMAXI;
    if (valid && tid < p3) {
      bw = logf(e_i / Z3f) + gumbel_at((unsigned)row * (unsigned)VOC + idx_i);
      bi = (int)idx_i;
    }
    for (int o = 32; o > 0; o >>= 1) {
      float ow = __shfl_down(bw, o);
      int   oi = __shfl_down(bi, o);
      if (ow > bw || (ow == bw && oi < bi)) { bw = ow; bi = oi; }
    }
    if ((tid & 63) == 0) { redw[tid >> 6] = bw; redi[tid >> 6] = bi; }
    __syncthreads();
    if (tid == 0) {
      float w = redw[0]; int ii = redi[0];
      for (int i = 1; i < 16; ++i)
        if (redw[i] > w || (redw[i] == w && redi[i] < ii)) { w = redw[i]; ii = redi[i]; }
      out[row] = ii;
    }
    return;
  }

  // ==================== HEAVY PATH (k inactive / recapture invalid) ========
  {
    float lmax = -INFINITY;
    FOR_ALL( (void)idx; lmax = fmaxf(lmax, x); )
    for (int o = 32; o > 0; o >>= 1) lmax = fmaxf(lmax, __shfl_down(lmax, o));
    if ((tid & 63) == 0) redw[tid >> 6] = lmax;
    __syncthreads();
    if (tid == 0) {
      float mm = redw[0];
      for (int i = 1; i < 16; ++i) mm = fmaxf(mm, redw[i]);
      sh_m = mm;
    }
    __syncthreads();
  }
  const float m = sh_m;

  unsigned tk_key = 0u; int rem_k = 0;
  if (ka) {
    for (int i = tid; i < NBINS; i += TPB) Hc[i] = 0u;
    __syncthreads();
    FOR_ALL( (void)idx; atomicAdd(&Hc[fkey(x) >> 21], 1u); )
    __syncthreads();
    scan32g(Hc, NBINS, tid, TPB);
    unsigned kku = (unsigned)k;
    for (int i = tid; i < NBINS; i += TPB) {
      unsigned hi = Hc[i], hn = (i + 1 < NBINS) ? Hc[i + 1] : 0u;
      if (hi >= kku && hn < kku) { sh_b0 = i; sh_above = hn; }
    }
    __syncthreads();
    const int b0 = sh_b0; kku -= sh_above;
    __syncthreads();
    for (int i = tid; i < NBINS; i += TPB) Hc[i] = 0u;
    __syncthreads();
    FOR_ALL(
      (void)idx;
      unsigned key = fkey(x);
      if ((int)(key >> 21) == b0) atomicAdd(&Hc[(key >> 10) & 0x7FFu], 1u);
    )
    __syncthreads();
    scan32g(Hc, NBINS, tid, TPB);
    for (int i = tid; i < NBINS; i += TPB) {
      unsigned hi = Hc[i], hn = (i + 1 < NBINS) ? Hc[i + 1] : 0u;
      if (hi >= kku && hn < kku) { sh_b1 = i; sh_above = hn; }
    }
    __syncthreads();
    const int b1 = sh_b1; kku -= sh_above;
    __syncthreads();
    for (int i = tid; i < NBINS; i += TPB) Hc[i] = 0u;
    __syncthreads();
    const unsigned pathk = ((unsigned)b0 << 11) | (unsigned)b1;
    FOR_ALL(
      (void)idx;
      unsigned key = fkey(x);
      if ((key >> 10) == pathk) atomicAdd(&Hc[key & 0x3FFu], 1u);
    )
    __syncthreads();
    scan32g(Hc, 1024, tid, TPB);
    for (int i = tid; i < 1024; i += TPB) {
      unsigned hi = Hc[i], hn = (i + 1 < 1024) ? Hc[i + 1] : 0u;
      if (hi >= kku && hn < kku) { sh_b2 = i; sh_above = hn; }
    }
    __syncthreads();
    rem_k = (int)(kku - sh_above);
    tk_key = ((unsigned)b0 << 21) | ((unsigned)b1 << 10) | (unsigned)sh_b2;
    __syncthreads();
  }
  const bool hk = ka;
  const float e_tk = hk ? expf(keyf(tk_key) - m) : 0.0f;
  const unsigned long long e_tk_fix = (unsigned long long)((double)e_tk * FIXS);
  unsigned long long* H = A;
  for (int i = tid; i < NBINS; i += TPB) H[i] = 0ull;
  __syncthreads();
  FOR_ALL(
    (void)idx;
    unsigned key = fkey(x);
    if (!hk || key > tk_key) {
      float e = expf(x - m);
      unsigned long long ef = (unsigned long long)((double)e * FIXS);
      if (ef) atomicAdd(&H[key >> 21], ef);
    }
  )
  __syncthreads();
  if (tid == 0 && hk) H[tk_key >> 21] += (unsigned long long)(unsigned)rem_k * e_tk_fix;
  __syncthreads();
  scan64(H, NBINS, tid);
  const unsigned long long Z1fix = H[0];
  const unsigned long long Tfix = (unsigned long long)((double)topp * (double)Z1fix);
  const int keepall = (Z1fix <= Tfix);

  unsigned t2_key = 0u; int rem2 = 0, all_mode = 0;
  double Z2d = 0.0; float e_t = 0.0f;

  if (!keepall) {
    for (int i = tid; i < NBINS; i += TPB) {
      unsigned long long hi = H[i], hn = (i + 1 < NBINS) ? H[i + 1] : 0ull;
      if (hi > Tfix && hn <= Tfix) { sh_b0 = i; sh_ab64 = hn; }
    }
    __syncthreads();
    const int b0p = sh_b0;
    const unsigned long long S0 = sh_ab64;
    __syncthreads();
    for (int i = tid; i < NBINS; i += TPB) H[i] = 0ull;
    __syncthreads();
    FOR_ALL(
      (void)idx;
      unsigned key = fkey(x);
      if ((int)(key >> 21) == b0p && (!hk || key > tk_key)) {
        float e = expf(x - m);
        unsigned long long ef = (unsigned long long)((double)e * FIXS);
        if (ef) atomicAdd(&H[(key >> 10) & 0x7FFu], ef);
      }
    )
    __syncthreads();
    if (tid == 0 && hk && (int)(tk_key >> 21) == b0p)
      H[(tk_key >> 10) & 0x7FFu] += (unsigned long long)(unsigned)rem_k * e_tk_fix;
    __syncthreads();
    scan64(H, NBINS, tid);
    {
      const unsigned long long T1 = Tfix - S0;
      for (int i = tid; i < NBINS; i += TPB) {
        unsigned long long hi = H[i], hn = (i + 1 < NBINS) ? H[i + 1] : 0ull;
        if (hi > T1 && hn <= T1) { sh_b1 = i; sh_ab64 = hn; }
      }
    }
    __syncthreads();
    const int b1p = sh_b1;
    const unsigned long long S1 = S0 + sh_ab64;
    __syncthreads();
    for (int i = tid; i < NBINS; i += TPB) H[i] = 0ull;
    for (int i = tid; i < 1024; i += TPB) Hc[i] = 0u;
    __syncthreads();
    const unsigned pathp = ((unsigned)b0p << 11) | (unsigned)b1p;
    FOR_ALL(
      (void)idx;
      unsigned key = fkey(x);
      if ((key >> 10) == pathp && (!hk || key > tk_key)) {
        float e = expf(x - m);
        unsigned long long ef = (unsigned long long)((double)e * FIXS);
        atomicAdd(&H[key & 0x3FFu], ef);
        atomicAdd(&Hc[key & 0x3FFu], 1u);
      }
    )
    __syncthreads();
    if (tid == 0 && hk && (tk_key >> 10) == pathp) {
      H[tk_key & 0x3FFu] += (unsigned long long)(unsigned)rem_k * e_tk_fix;
      Hc[tk_key & 0x3FFu] += (unsigned)rem_k;
    }
    __syncthreads();
    scan64(H, 1024, tid);
    {
      const unsigned long long T2 = Tfix - S1;
      for (int i = tid; i < 1024; i += TPB) {
        unsigned long long hi = H[i], hn = (i + 1 < 1024) ? H[i + 1] : 0ull;
        if (hi > T2 && hn <= T2) { sh_b2 = i; sh_ab64 = hn; }
      }
    }
    __syncthreads();
    const int b2p = sh_b2;
    const unsigned long long Sfix = S1 + sh_ab64;
    t2_key = ((unsigned)b0p << 21) | ((unsigned)b1p << 10) | (unsigned)b2p;
    const int c_t2 = (int)Hc[b2p];
    e_t = expf(keyf(t2_key) - m);
    const double Td = (double)topp * ((double)Z1fix / FIXS);
    const double Sd = (double)Sfix / FIXS;
    const double jmd = (Td - Sd) / (double)e_t;
    int rem_p;
    if (jmd >= (double)c_t2) rem_p = c_t2;
    else {
      rem_p = (int)jmd + 1;
      if (rem_p > c_t2) rem_p = c_t2;
      if (rem_p < 1) rem_p = 1;
    }
    rem2 = rem_p;
    const unsigned long long Z2fix =
        Sfix + (unsigned long long)(unsigned)rem_p *
                   (unsigned long long)((double)e_t * FIXS);
    Z2d = (double)Z2fix / FIXS;
  } else {
    if (hk) { t2_key = tk_key; rem2 = rem_k; e_t = e_tk; }
    else    { all_mode = 1; }
    Z2d = (double)Z1fix / FIXS;
  }

  if (tid == 0) { sh_tn = 0; sh_I2 = IMAXI; }
  __syncthreads();
  const float Z2f = (float)Z2d;
  const float thrm = minp * (1.0f / Z2f);
  double zp = 0.0;
  FOR_ALL(
    unsigned key = fkey(x);
    if (all_mode || key > t2_key) {
      float e = expf(x - m);
      float q1 = e / Z2f;
      if (!(q1 < thrm)) zp += (double)e;
    } else if (key == t2_key) {
      int p = atomicAdd(&sh_tn, 1);
      if (p < TIE_CAP) Hc[p] = (unsigned)idx;
    }
  )
  for (int o = 32; o > 0; o >>= 1) zp += __shfl_down(zp, o);
  if ((tid & 63) == 0) redd[tid >> 6] = zp;
  __syncthreads();
  int class_ok = 1;
  if (!all_mode) { float q1t = e_t / Z2f; class_ok = !(q1t < thrm); }
  if (tid == 0) {
    double z3 = 0.0;
    for (int i = 0; i < 16; ++i) z3 += redd[i];
    if (!all_mode && class_ok) z3 += (double)rem2 * (double)e_t;
    sh_Z3 = z3;
  }
  __syncthreads();
  const int tn = sh_tn;
  if (!all_mode && rem2 < tn && tn <= TIE_CAP) {
    if (tid < tn) {
      unsigned mine = Hc[tid];
      int r = 0;
      for (int j = 0; j < tn; ++j) r += (Hc[j] < mine);
      if (r == rem2 - 1) sh_I2 = (int)mine;
    }
  }
  __syncthreads();
  const int I2 = sh_I2;
  const float Z3f = (float)sh_Z3;
  float bw = -INFINITY; int bi = IMAXI;
  FOR_ALL(
    unsigned key = fkey(x);
    bool kp = all_mode || key > t2_key || (key == t2_key && idx <= I2);
    if (kp) {
      float e = expf(x - m);
      float q1 = e / Z2f;
      if (!(q1 < thrm)) {
        float w = logf(e / Z3f) + gumbel_at((unsigned)row * (unsigned)VOC + (unsigned)idx);
        if (w > bw) { bw = w; bi = idx; }
        else if (w == bw && idx < bi) bi = idx;
      }
    }
  )
  for (int o = 32; o > 0; o >>= 1) {
    float ow = __shfl_down(bw, o);
    int   oi = __shfl_down(bi, o);
    if (ow > bw || (ow == bw && oi < bi)) { bw = ow; bi = oi; }
  }
  if ((tid & 63) == 0) { redw[tid >> 6] = bw; redi[tid >> 6] = bi; }
  __syncthreads();
  if (tid == 0) {
    float w = redw[0]; int ii = redi[0];
    for (int i = 1; i < 16; ++i)
      if (redw[i] > w || (redw[i] == w && redi[i] < ii)) { w = redw[i]; ii = redi[i]; }
    out[row] = ii;
  }
}

extern "C" void kernel_launch(void* const* d_in, const int* in_sizes, int n_in,
                              void* d_out, int out_size, void* d_ws, size_t ws_size,
                              hipStream_t stream) {
  (void)n_in; (void)ws_size; (void)out_size;
  const float* logits = (const float*)d_in[0];
  const float* temps  = (const float*)d_in[1];
  const float* topps  = (const float*)d_in[2];
  const int*   topks  = (const int*)d_in[3];
  const float* minps  = (const float*)d_in[4];
  int* out = (int*)d_out;
  const int rows = in_sizes[1];   // B = 128
  unsigned char* ws = (unsigned char*)d_ws;
  hipMemsetAsync(ws + WS_DONE, 0, rows * sizeof(unsigned), stream);
  sampler_fused<<<dim3(rows * 4), dim3(TPB), 0, stream>>>(
      logits, temps, topps, topks, minps, ws, out);
}

// Round 11
// 125.303 us; speedup vs baseline: 3.3226x; 3.3226x over previous
//
#include <hip/hip_runtime.h>

// BatchSampler rnd11: REVERT to verified rnd8 (126.4us, absmax 0).
// rnd9/rnd10 fused single-kernel variants both regressed to ~350us: the
// in-kernel cross-XCD producer->consumer handoff (last-block-done) pushed all
// rows into the heavy fallback despite agent-scoped atomics; the kernel
// boundary below is the only reliable cross-XCD flush (~5us cost).
// K3 (8 blk/row x 512): stream row; capture raw logit >= 2.25 (fixed threshold,
//   ~1567+-39 hits/row on N(0,1); validated in K4) into LDS staging; write count
//   + entries to a PRIVATE per-block segment (320 entries) -- no global atomics,
//   no counter memset. Only kernel touching the full 65.7 MB.
// K4 (1 blk/row x 1024): gather 8 segments; validate (k<=1024, counts<=320,
//   k<=n<=2048) else verified heavy fallback; hybrid bitonic sort of 2048
//   (x desc, idx asc = exact reference rank order): cross-wave strides (>=64)
//   via LDS+barrier, strides <=32 in-register via __shfl_xor; wave-shuffle
//   prefix scan; verified tail (top-p cut, min-p cut, gumbel argmax via
//   threefry-partitionable, key=(0,42)).

#define TPS 512
#define TPB 1024
#define VOC 128256
#define V4 (VOC / 4)          // 32064
#define NBINS 2048
#define SEG 320               // per-block capture segment (count bound +8.9σ)
#define CAPROW (8 * SEG)      // 2560 staging entries per row
#define CAP2 2048             // sort size
#define TIE_CAP 1024
#define IMAXI 0x7fffffff
#define FIXS 1.7592186044416e13   // 2^44
#define THRK 0xC0100000u      // fkey(2.25f): raw-logit capture threshold

// ws layout (bytes)
#define WS_CNT 0                               // u32 [128][8] = 4 KB
#define WS_CAP 4096                            // u64 [128][CAPROW] = 2.5 MB

__device__ __forceinline__ unsigned fkey(float x) {
  unsigned b = __float_as_uint(x);
  return b ^ ((b & 0x80000000u) ? 0xFFFFFFFFu : 0x80000000u);
}
__device__ __forceinline__ float keyf(unsigned k) {
  unsigned b = (k & 0x80000000u) ? (k ^ 0x80000000u) : ~k;
  return __uint_as_float(b);
}
__device__ __forceinline__ unsigned rotl32(unsigned v, int r) {
  return (v << r) | (v >> (32 - r));
}

// JAX threefry2x32, key=(0,42), partitionable path: counters (0,i), out o1^o2.
__device__ __forceinline__ float gumbel_at(unsigned i) {
  const unsigned ks1 = 42u;
  const unsigned ks2 = 0x1BD11BDAu ^ 42u;
  unsigned x0 = 0u;
  unsigned x1 = i + ks1;
  x0 += x1; x1 = rotl32(x1, 13); x1 ^= x0;
  x0 += x1; x1 = rotl32(x1, 15); x1 ^= x0;
  x0 += x1; x1 = rotl32(x1, 26); x1 ^= x0;
  x0 += x1; x1 = rotl32(x1, 6);  x1 ^= x0;
  x0 += ks1; x1 += ks2 + 1u;
  x0 += x1; x1 = rotl32(x1, 17); x1 ^= x0;
  x0 += x1; x1 = rotl32(x1, 29); x1 ^= x0;
  x0 += x1; x1 = rotl32(x1, 16); x1 ^= x0;
  x0 += x1; x1 = rotl32(x1, 24); x1 ^= x0;
  x0 += ks2; x1 += 0u + 2u;
  x0 += x1; x1 = rotl32(x1, 13); x1 ^= x0;
  x0 += x1; x1 = rotl32(x1, 15); x1 ^= x0;
  x0 += x1; x1 = rotl32(x1, 26); x1 ^= x0;
  x0 += x1; x1 = rotl32(x1, 6);  x1 ^= x0;
  x0 += 0u; x1 += ks1 + 3u;
  x0 += x1; x1 = rotl32(x1, 17); x1 ^= x0;
  x0 += x1; x1 = rotl32(x1, 29); x1 ^= x0;
  x0 += x1; x1 = rotl32(x1, 16); x1 ^= x0;
  x0 += x1; x1 = rotl32(x1, 24); x1 ^= x0;
  x0 += ks1; x1 += ks2 + 4u;
  x0 += x1; x1 = rotl32(x1, 13); x1 ^= x0;
  x0 += x1; x1 = rotl32(x1, 15); x1 ^= x0;
  x0 += x1; x1 = rotl32(x1, 26); x1 ^= x0;
  x0 += x1; x1 = rotl32(x1, 6);  x1 ^= x0;
  x0 += ks2; x1 += 0u + 5u;
  unsigned bits = x0 ^ x1;
  unsigned fb = (bits >> 9) | 0x3f800000u;
  float f = __uint_as_float(fb) - 1.0f;
  float u = (f > 0.0f) ? f : 1.17549435e-38f;
  return -logf(-logf(u));
}

// In-register bitonic merge step: strides maxs..1 (maxs<=32) inside a 64-wave.
__device__ __forceinline__ unsigned long long bmerge(
    unsigned long long v, int i, int size, int maxs) {
  const bool up = ((i & size) == 0);
  for (int s = maxs; s > 0; s >>= 1) {
    unsigned long long p = __shfl_xor(v, s, 64);
    bool keep_min = (up == ((i & s) == 0));
    bool take = keep_min ? (p < v) : (p > v);
    if (take) v = p;
  }
  return v;
}

// Inclusive suffix scan, generic block size (n/tpb <= 4)
__device__ __forceinline__ void scan32g(unsigned* H, int n, int tid, int tpb) {
  for (int d = 1; d < n; d <<= 1) {
    unsigned v[4]; int c = 0;
    for (int i = tid; i < n; i += tpb) {
      v[c] = H[i] + ((i + d < n) ? H[i + d] : 0u);
      ++c;
    }
    __syncthreads();
    c = 0;
    for (int i = tid; i < n; i += tpb) { H[i] = v[c]; ++c; }
    __syncthreads();
  }
}
__device__ __forceinline__ void scan64(unsigned long long* H, int n, int tid) {
  for (int d = 1; d < n; d <<= 1) {
    unsigned long long v0 = 0ull, v1 = 0ull;
    int i0 = tid, i1 = tid + TPB;
    bool a0 = (i0 < n), a1 = (i1 < n);
    if (a0) { v0 = H[i0]; if (i0 + d < n) v0 += H[i0 + d]; }
    if (a1) { v1 = H[i1]; if (i1 + d < n) v1 += H[i1 + d]; }
    __syncthreads();
    if (a0) H[i0] = v0;
    if (a1) H[i1] = v1;
    __syncthreads();
  }
}

// Full-row stream for K4 heavy path (TPB threads)
#define FOR_ALL(...)                                                          \
  for (int c_ = 0; c_ < 32; ++c_) {                                           \
    const int i4_ = c_ * TPB + tid;                                           \
    if (i4_ < V4) {                                                           \
      const float4 L_ = ((const float4*)rowp)[i4_];                           \
      const float xs_[4] = { L_.x / tclamp, L_.y / tclamp,                    \
                             L_.z / tclamp, L_.w / tclamp };                  \
      const int base_ = i4_ * 4;                                              \
      for (int j_ = 0; j_ < 4; ++j_) {                                        \
        const int idx = base_ + j_; const float x = xs_[j_];                  \
        __VA_ARGS__                                                           \
      }                                                                       \
    }                                                                         \
  }

// ==================== K3: capture (fixed threshold, private segments) =======
extern "C" __global__ void __launch_bounds__(TPS)
k3_capture(const float* __restrict__ logits, const float* __restrict__ temps,
           unsigned char* __restrict__ ws)
{
  __shared__ unsigned long long Ls[SEG];
  __shared__ unsigned sh_nloc;
  const int blk = blockIdx.x, row = blk >> 3, sb = blk & 7;
  const int tid = threadIdx.x;
  const float* rowp = logits + (size_t)row * VOC;
  const float tclamp = fmaxf(temps[row], 1e-8f);
  if (tid == 0) sh_nloc = 0u;
  __syncthreads();
  for (int c = 0; c < 8; ++c) {
    const int i4 = c * 4096 + sb * TPS + tid;
    if (i4 < V4) {
      const float4 L = ((const float4*)rowp)[i4];
      const float v[4] = { L.x, L.y, L.z, L.w };
      const int base = i4 * 4;
      for (int j = 0; j < 4; ++j) {
        if (fkey(v[j]) >= THRK) {
          float x = v[j] / tclamp;
          unsigned kx = fkey(x);
          unsigned p = atomicAdd(&sh_nloc, 1u);
          if (p < SEG)
            Ls[p] = ((unsigned long long)(~kx) << 32) | (unsigned)(base + j);
        }
      }
    }
  }
  __syncthreads();
  const unsigned nloc = sh_nloc;    // raw count; >SEG flags overflow for K4
  if (tid == 0) ((unsigned*)(ws + WS_CNT))[row * 8 + sb] = nloc;
  unsigned long long* cap = (unsigned long long*)(ws + WS_CAP) +
                            (size_t)row * CAPROW + (size_t)sb * SEG;
  const unsigned nw = min(nloc, (unsigned)SEG);
  for (unsigned i = tid; i < nw; i += TPS) cap[i] = Ls[i];
}

// ==================== K4: gather + sort + select + sample ====================
extern "C" __global__ void __launch_bounds__(TPB)
k4_sample(const float* __restrict__ logits, const float* __restrict__ temps,
          const float* __restrict__ topps, const int* __restrict__ topks,
          const float* __restrict__ minps, const unsigned char* __restrict__ ws,
          int* __restrict__ out)
{
  __shared__ unsigned long long A[CAP2];  // 16 KB: sort buf / heavy u64 hist
  __shared__ unsigned Hc[NBINS];          // 8 KB: heavy counts / tie list
  __shared__ double D[TPB];               // 8 KB prefix sums
  __shared__ float redw[16];
  __shared__ int   redi[16];
  __shared__ double redd[16];
  __shared__ int segoff[9];
  __shared__ int sh_bad;
  __shared__ float sh_m;
  __shared__ int sh_b0, sh_b1, sh_b2;
  __shared__ unsigned sh_above;
  __shared__ unsigned long long sh_ab64;
  __shared__ int sh_p, sh_tn, sh_I2;
  __shared__ double sh_Z3;

  const int tid = threadIdx.x;
  const int row = blockIdx.x;
  const float* rowp = logits + (size_t)row * VOC;
  const float tclamp = fmaxf(temps[row], 1e-8f);
  const float topp = topps[row];
  const float minp = minps[row];
  const int k = topks[row];
  const bool ka = (k > 0) && (k < VOC);

  if (tid == 0) {
    const unsigned* cnts = (const unsigned*)(ws + WS_CNT) + row * 8;
    int acc = 0, bad = 0;
    for (int b = 0; b < 8; ++b) {
      segoff[b] = acc;
      unsigned c = cnts[b];
      if (c > SEG) bad = 1;
      acc += (int)c;
    }
    segoff[8] = acc;
    sh_bad = bad;
  }
  __syncthreads();
  const int n = segoff[8];

  if (ka && k <= TPB && !sh_bad && n >= k && n <= CAP2) {
    // ==================== FAST PATH ====================
    const unsigned long long* capr =
        (const unsigned long long*)(ws + WS_CAP) + (size_t)row * CAPROW;
    for (int b = 0; b < 8; ++b) {
      const int off = segoff[b], cnt = segoff[b + 1] - off;
      for (int i = tid; i < cnt; i += TPB) A[off + i] = capr[b * SEG + i];
    }
    for (int i = n + tid; i < CAP2; i += TPB) A[i] = ~0ull;
    __syncthreads();
    // ---- hybrid bitonic sort, 2048 fixed: (~xkey,idx) asc == x desc, idx asc
    const int lane = tid & 63, wave = tid >> 6;
    for (int g = wave; g < 32; g += 16) {       // sizes 2..64 in-register
      const int i = g * 64 + lane;
      unsigned long long v = A[i];
      v = bmerge(v, i, 2, 1);
      v = bmerge(v, i, 4, 2);
      v = bmerge(v, i, 8, 4);
      v = bmerge(v, i, 16, 8);
      v = bmerge(v, i, 32, 16);
      v = bmerge(v, i, 64, 32);
      A[i] = v;
    }
    __syncthreads();
    for (int size = 128; size <= CAP2; size <<= 1) {
      for (int stride = size >> 1; stride >= 64; stride >>= 1) {  // cross-wave
        for (int r = 0; r < 2; ++r) {
          const int i = tid + (r << 10);
          const int j = i ^ stride;
          if (j > i) {
            unsigned long long a = A[i], b = A[j];
            bool up = ((i & size) == 0);
            if ((a > b) == up) { A[i] = b; A[j] = a; }
          }
        }
        __syncthreads();
      }
      for (int g = wave; g < 32; g += 16) {     // strides 32..1 in-register
        const int i = g * 64 + lane;
        A[i] = bmerge(A[i], i, size, 32);
      }
      __syncthreads();
    }
    // ---- verified fast tail on positions 0..k-1 ----
    const float m = keyf(~(unsigned)(A[0] >> 32));   // max x
    unsigned idx_i = 0u; float e_i = 0.0f;
    const bool valid = (tid < k);
    if (valid) {
      unsigned long long a = A[tid];
      idx_i = (unsigned)a;
      e_i = expf(keyf(~(unsigned)(a >> 32)) - m);
    }
    // wave-shuffle inclusive prefix scan of e_i
    double v = valid ? (double)e_i : 0.0;
    for (int o = 1; o < 64; o <<= 1) {
      double t = __shfl_up(v, o);
      if ((tid & 63) >= o) v += t;
    }
    if ((tid & 63) == 63) redd[tid >> 6] = v;
    __syncthreads();
    if (tid == 0) {
      double acc = 0.0;
      for (int w = 0; w < 16; ++w) { double t = redd[w]; redd[w] = acc; acc += t; }
    }
    __syncthreads();
    v += redd[tid >> 6];
    D[tid] = v;
    __syncthreads();
    const double Z1 = D[k - 1];
    const double T = (double)topp * Z1;
    if (tid == 0) sh_p = 0;
    __syncthreads();
    if (valid) {
      bool kept = (tid == 0) || (D[tid - 1] <= T);
      if (kept) atomicMax(&sh_p, tid);
    }
    __syncthreads();
    const int p2 = sh_p + 1;
    const float Z2f = (float)D[p2 - 1];
    const float e0 = expf(0.0f);                     // top element: x-m == 0
    const float thrm = minp * (e0 / Z2f);
    __syncthreads();
    if (tid == 0) sh_p = 0;
    __syncthreads();
    if (valid && tid < p2) {
      float q = e_i / Z2f;
      if (!(q < thrm)) atomicMax(&sh_p, tid);
    }
    __syncthreads();
    const int p3 = sh_p + 1;
    const float Z3f = (float)D[p3 - 1];
    float bw = -INFINITY; int bi = IMAXI;
    if (valid && tid < p3) {
      bw = logf(e_i / Z3f) + gumbel_at((unsigned)row * (unsigned)VOC + idx_i);
      bi = (int)idx_i;
    }
    for (int o = 32; o > 0; o >>= 1) {
      float ow = __shfl_down(bw, o);
      int   oi = __shfl_down(bi, o);
      if (ow > bw || (ow == bw && oi < bi)) { bw = ow; bi = oi; }
    }
    if ((tid & 63) == 0) { redw[tid >> 6] = bw; redi[tid >> 6] = bi; }
    __syncthreads();
    if (tid == 0) {
      float w = redw[0]; int ii = redi[0];
      for (int i = 1; i < 16; ++i)
        if (redw[i] > w || (redw[i] == w && redi[i] < ii)) { w = redw[i]; ii = redi[i]; }
      out[row] = ii;
    }
    return;
  }

  // ==================== HEAVY PATH (k inactive / capture invalid) ==========
  {
    float lmax = -INFINITY;
    FOR_ALL( (void)idx; lmax = fmaxf(lmax, x); )
    for (int o = 32; o > 0; o >>= 1) lmax = fmaxf(lmax, __shfl_down(lmax, o));
    if ((tid & 63) == 0) redw[tid >> 6] = lmax;
    __syncthreads();
    if (tid == 0) {
      float mm = redw[0];
      for (int i = 1; i < 16; ++i) mm = fmaxf(mm, redw[i]);
      sh_m = mm;
    }
    __syncthreads();
  }
  const float m = sh_m;

  unsigned tk_key = 0u; int rem_k = 0;
  if (ka) {
    for (int i = tid; i < NBINS; i += TPB) Hc[i] = 0u;
    __syncthreads();
    FOR_ALL( (void)idx; atomicAdd(&Hc[fkey(x) >> 21], 1u); )
    __syncthreads();
    scan32g(Hc, NBINS, tid, TPB);
    unsigned kku = (unsigned)k;
    for (int i = tid; i < NBINS; i += TPB) {
      unsigned hi = Hc[i], hn = (i + 1 < NBINS) ? Hc[i + 1] : 0u;
      if (hi >= kku && hn < kku) { sh_b0 = i; sh_above = hn; }
    }
    __syncthreads();
    const int b0 = sh_b0; kku -= sh_above;
    __syncthreads();
    for (int i = tid; i < NBINS; i += TPB) Hc[i] = 0u;
    __syncthreads();
    FOR_ALL(
      (void)idx;
      unsigned key = fkey(x);
      if ((int)(key >> 21) == b0) atomicAdd(&Hc[(key >> 10) & 0x7FFu], 1u);
    )
    __syncthreads();
    scan32g(Hc, NBINS, tid, TPB);
    for (int i = tid; i < NBINS; i += TPB) {
      unsigned hi = Hc[i], hn = (i + 1 < NBINS) ? Hc[i + 1] : 0u;
      if (hi >= kku && hn < kku) { sh_b1 = i; sh_above = hn; }
    }
    __syncthreads();
    const int b1 = sh_b1; kku -= sh_above;
    __syncthreads();
    for (int i = tid; i < NBINS; i += TPB) Hc[i] = 0u;
    __syncthreads();
    const unsigned pathk = ((unsigned)b0 << 11) | (unsigned)b1;
    FOR_ALL(
      (void)idx;
      unsigned key = fkey(x);
      if ((key >> 10) == pathk) atomicAdd(&Hc[key & 0x3FFu], 1u);
    )
    __syncthreads();
    scan32g(Hc, 1024, tid, TPB);
    for (int i = tid; i < 1024; i += TPB) {
      unsigned hi = Hc[i], hn = (i + 1 < 1024) ? Hc[i + 1] : 0u;
      if (hi >= kku && hn < kku) { sh_b2 = i; sh_above = hn; }
    }
    __syncthreads();
    rem_k = (int)(kku - sh_above);
    tk_key = ((unsigned)b0 << 21) | ((unsigned)b1 << 10) | (unsigned)sh_b2;
    __syncthreads();
  }
  const bool hk = ka;
  const float e_tk = hk ? expf(keyf(tk_key) - m) : 0.0f;
  const unsigned long long e_tk_fix = (unsigned long long)((double)e_tk * FIXS);
  unsigned long long* H = A;
  for (int i = tid; i < NBINS; i += TPB) H[i] = 0ull;
  __syncthreads();
  FOR_ALL(
    (void)idx;
    unsigned key = fkey(x);
    if (!hk || key > tk_key) {
      float e = expf(x - m);
      unsigned long long ef = (unsigned long long)((double)e * FIXS);
      if (ef) atomicAdd(&H[key >> 21], ef);
    }
  )
  __syncthreads();
  if (tid == 0 && hk) H[tk_key >> 21] += (unsigned long long)(unsigned)rem_k * e_tk_fix;
  __syncthreads();
  scan64(H, NBINS, tid);
  const unsigned long long Z1fix = H[0];
  const unsigned long long Tfix = (unsigned long long)((double)topp * (double)Z1fix);
  const int keepall = (Z1fix <= Tfix);

  unsigned t2_key = 0u; int rem2 = 0, all_mode = 0;
  double Z2d = 0.0; float e_t = 0.0f;

  if (!keepall) {
    for (int i = tid; i < NBINS; i += TPB) {
      unsigned long long hi = H[i], hn = (i + 1 < NBINS) ? H[i + 1] : 0ull;
      if (hi > Tfix && hn <= Tfix) { sh_b0 = i; sh_ab64 = hn; }
    }
    __syncthreads();
    const int b0p = sh_b0;
    const unsigned long long S0 = sh_ab64;
    __syncthreads();
    for (int i = tid; i < NBINS; i += TPB) H[i] = 0ull;
    __syncthreads();
    FOR_ALL(
      (void)idx;
      unsigned key = fkey(x);
      if ((int)(key >> 21) == b0p && (!hk || key > tk_key)) {
        float e = expf(x - m);
        unsigned long long ef = (unsigned long long)((double)e * FIXS);
        if (ef) atomicAdd(&H[(key >> 10) & 0x7FFu], ef);
      }
    )
    __syncthreads();
    if (tid == 0 && hk && (int)(tk_key >> 21) == b0p)
      H[(tk_key >> 10) & 0x7FFu] += (unsigned long long)(unsigned)rem_k * e_tk_fix;
    __syncthreads();
    scan64(H, NBINS, tid);
    {
      const unsigned long long T1 = Tfix - S0;
      for (int i = tid; i < NBINS; i += TPB) {
        unsigned long long hi = H[i], hn = (i + 1 < NBINS) ? H[i + 1] : 0ull;
        if (hi > T1 && hn <= T1) { sh_b1 = i; sh_ab64 = hn; }
      }
    }
    __syncthreads();
    const int b1p = sh_b1;
    const unsigned long long S1 = S0 + sh_ab64;
    __syncthreads();
    for (int i = tid; i < NBINS; i += TPB) H[i] = 0ull;
    for (int i = tid; i < 1024; i += TPB) Hc[i] = 0u;
    __syncthreads();
    const unsigned pathp = ((unsigned)b0p << 11) | (unsigned)b1p;
    FOR_ALL(
      (void)idx;
      unsigned key = fkey(x);
      if ((key >> 10) == pathp && (!hk || key > tk_key)) {
        float e = expf(x - m);
        unsigned long long ef = (unsigned long long)((double)e * FIXS);
        atomicAdd(&H[key & 0x3FFu], ef);
        atomicAdd(&Hc[key & 0x3FFu], 1u);
      }
    )
    __syncthreads();
    if (tid == 0 && hk && (tk_key >> 10) == pathp) {
      H[tk_key & 0x3FFu] += (unsigned long long)(unsigned)rem_k * e_tk_fix;
      Hc[tk_key & 0x3FFu] += (unsigned)rem_k;
    }
    __syncthreads();
    scan64(H, 1024, tid);
    {
      const unsigned long long T2 = Tfix - S1;
      for (int i = tid; i < 1024; i += TPB) {
        unsigned long long hi = H[i], hn = (i + 1 < 1024) ? H[i + 1] : 0ull;
        if (hi > T2 && hn <= T2) { sh_b2 = i; sh_ab64 = hn; }
      }
    }
    __syncthreads();
    const int b2p = sh_b2;
    const unsigned long long Sfix = S1 + sh_ab64;
    t2_key = ((unsigned)b0p << 21) | ((unsigned)b1p << 10) | (unsigned)b2p;
    const int c_t2 = (int)Hc[b2p];
    e_t = expf(keyf(t2_key) - m);
    const double Td = (double)topp * ((double)Z1fix / FIXS);
    const double Sd = (double)Sfix / FIXS;
    const double jmd = (Td - Sd) / (double)e_t;
    int rem_p;
    if (jmd >= (double)c_t2) rem_p = c_t2;
    else {
      rem_p = (int)jmd + 1;
      if (rem_p > c_t2) rem_p = c_t2;
      if (rem_p < 1) rem_p = 1;
    }
    rem2 = rem_p;
    const unsigned long long Z2fix =
        Sfix + (unsigned long long)(unsigned)rem_p *
                   (unsigned long long)((double)e_t * FIXS);
    Z2d = (double)Z2fix / FIXS;
  } else {
    if (hk) { t2_key = tk_key; rem2 = rem_k; e_t = e_tk; }
    else    { all_mode = 1; }
    Z2d = (double)Z1fix / FIXS;
  }

  if (tid == 0) { sh_tn = 0; sh_I2 = IMAXI; }
  __syncthreads();
  const float Z2f = (float)Z2d;
  const float thrm = minp * (1.0f / Z2f);
  double zp = 0.0;
  FOR_ALL(
    unsigned key = fkey(x);
    if (all_mode || key > t2_key) {
      float e = expf(x - m);
      float q1 = e / Z2f;
      if (!(q1 < thrm)) zp += (double)e;
    } else if (key == t2_key) {
      int p = atomicAdd(&sh_tn, 1);
      if (p < TIE_CAP) Hc[p] = (unsigned)idx;
    }
  )
  for (int o = 32; o > 0; o >>= 1) zp += __shfl_down(zp, o);
  if ((tid & 63) == 0) redd[tid >> 6] = zp;
  __syncthreads();
  int class_ok = 1;
  if (!all_mode) { float q1t = e_t / Z2f; class_ok = !(q1t < thrm); }
  if (tid == 0) {
    double z3 = 0.0;
    for (int i = 0; i < 16; ++i) z3 += redd[i];
    if (!all_mode && class_ok) z3 += (double)rem2 * (double)e_t;
    sh_Z3 = z3;
  }
  __syncthreads();
  const int tn = sh_tn;
  if (!all_mode && rem2 < tn && tn <= TIE_CAP) {
    if (tid < tn) {
      unsigned mine = Hc[tid];
      int r = 0;
      for (int j = 0; j < tn; ++j) r += (Hc[j] < mine);
      if (r == rem2 - 1) sh_I2 = (int)mine;
    }
  }
  __syncthreads();
  const int I2 = sh_I2;
  const float Z3f = (float)sh_Z3;
  float bw = -INFINITY; int bi = IMAXI;
  FOR_ALL(
    unsigned key = fkey(x);
    bool kp = all_mode || key > t2_key || (key == t2_key && idx <= I2);
    if (kp) {
      float e = expf(x - m);
      float q1 = e / Z2f;
      if (!(q1 < thrm)) {
        float w = logf(e / Z3f) + gumbel_at((unsigned)row * (unsigned)VOC + (unsigned)idx);
        if (w > bw) { bw = w; bi = idx; }
        else if (w == bw && idx < bi) bi = idx;
      }
    }
  )
  for (int o = 32; o > 0; o >>= 1) {
    float ow = __shfl_down(bw, o);
    int   oi = __shfl_down(bi, o);
    if (ow > bw || (ow == bw && oi < bi)) { bw = ow; bi = oi; }
  }
  if ((tid & 63) == 0) { redw[tid >> 6] = bw; redi[tid >> 6] = bi; }
  __syncthreads();
  if (tid == 0) {
    float w = redw[0]; int ii = redi[0];
    for (int i = 1; i < 16; ++i)
      if (redw[i] > w || (redw[i] == w && redi[i] < ii)) { w = redw[i]; ii = redi[i]; }
    out[row] = ii;
  }
}

extern "C" void kernel_launch(void* const* d_in, const int* in_sizes, int n_in,
                              void* d_out, int out_size, void* d_ws, size_t ws_size,
                              hipStream_t stream) {
  (void)n_in; (void)ws_size; (void)out_size;
  const float* logits = (const float*)d_in[0];
  const float* temps  = (const float*)d_in[1];
  const float* topps  = (const float*)d_in[2];
  const int*   topks  = (const int*)d_in[3];
  const float* minps  = (const float*)d_in[4];
  int* out = (int*)d_out;
  const int rows = in_sizes[1];   // B = 128
  unsigned char* ws = (unsigned char*)d_ws;
  k3_capture<<<dim3(rows * 8), dim3(TPS), 0, stream>>>(logits, temps, ws);
  k4_sample<<<dim3(rows), dim3(TPB), 0, stream>>>(logits, temps, topps, topks,
                                                  minps, ws, out);
}